// Round 1
// baseline (89.679 us; speedup 1.0000x reference)
//
#include <hip/hip_runtime.h>

#define NBATCH 8192
#define NELEC  16
#define NMO    32
#define NCONF  64
#define NS     8          // NUP == NDOWN == 8
#define TSTR   20         // A (fp32) row stride in floats (80 B: 16B-aligned for b128)
#define TSZ    (NMO * TSTR)
#define TSTRH  24         // D (fp16) row stride in HALVES (48 B: 16B-aligned for b128)
#define TSZH   (NMO * TSTRH)

typedef float    v2f   __attribute__((ext_vector_type(2)));
typedef _Float16 half8 __attribute__((ext_vector_type(8)));
typedef _Float16 half4 __attribute__((ext_vector_type(4)));

__device__ __forceinline__ v2f pkfma(v2f a, v2f b, v2f c) {
#if __has_builtin(__builtin_elementwise_fma)
    return __builtin_elementwise_fma(a, b, c);
#else
    return a * b + c;
#endif
}
__device__ __forceinline__ v2f bc2(float s) { return (v2f){s, s}; }
__device__ __forceinline__ float getel2(const v2f (&R)[4], int j) {
    return (j & 1) ? R[j >> 1].y : R[j >> 1].x;
}
__device__ __forceinline__ void setel2(v2f (&R)[4], int j, float v) {
    if (j & 1) R[j >> 1].y = v; else R[j >> 1].x = v;
}

// R13: DS-conflict attack (R12 model: DS pipe ~16-19 us of ~28 us kernel at
// 1.65x conflict factor; A-gather is ~475 of ~750 DS cyc/wave).
//  (1) cols sorted per-thread (19-CE Batcher net): tr(A'^-1 D') is invariant
//      under simultaneous row-permutation of A' and D'; det picks up
//      sign(perm) = swap parity of the network. Sorted cols make each A/D
//      read instr a j-th-order-statistic draw -> ~10 distinct LDS lines per
//      instr vs ~41 -> predicted conflict factor ~1.1x vs measured 1.65x.
//  (2) spin-pure waves (wave = batch x spin, lane = config): no up/dn line
//      mixing inside one instr, eoff wave-uniform; spins combine via a 1 KB
//      LDS exchange + barrier (replaces shfl_xor lane-pair combine).
//  (3) staging: column-quad global loads (coalesce as 2x128B segments) +
//      ONE ds_write_b128 (A) / ds_write_b64 (D) per thread. Old transposed
//      b32 scatter writes were inherently 4-way conflicted (dc=8 -> dbank=0
//      at any 16B-aligned stride).
// R11/R12 numerics stand: A stays fp32 (fp16-A amplified by kappa -> 4e8);
// D fp16 fine (enters linearly). R8 lesson: gathers stay in LDS, not global.
__device__ __forceinline__ void solve8T(const float* __restrict__ MOT,
                                        const _Float16* __restrict__ D2T,
                                        const int (&cols)[NS], int eoff,
                                        float& det_out, float& tr_out)
{
    v2f A2[NS][4];                    // row j, pair p = cols {2p, 2p+1}
    #pragma unroll
    for (int j = 0; j < NS; ++j) {
        const float4* pa = (const float4*)(MOT + cols[j] * TSTR + eoff);
        float4 a0 = pa[0], a1 = pa[1];
        A2[j][0] = (v2f){a0.x, a0.y};
        A2[j][1] = (v2f){a0.z, a0.w};
        A2[j][2] = (v2f){a1.x, a1.y};
        A2[j][3] = (v2f){a1.z, a1.w};
    }

    // In-place LU, no pivot (packed over column pairs) — byte-identical to R7.
    float det = 1.0f;
    #pragma unroll
    for (int k = 0; k < NS; ++k) {
        float ukk = getel2(A2[k], k);
        det *= ukk;
        float pinv = __builtin_amdgcn_rcpf(ukk);
        #pragma unroll
        for (int r = k + 1; r < NS; ++r) {
            float m = getel2(A2[r], k) * pinv;
            v2f m2 = bc2(m);
            #pragma unroll
            for (int p = (k + 1) >> 1; p < 4; ++p)
                A2[r][p] = pkfma(-m2, A2[k][p], A2[r][p]);
            setel2(A2[r], k, m);
        }
        setel2(A2[k], k, pinv);
    }

    // tr = sum_k <x(k), row_k(D')> with A' x(k) = e_k; k pairs in lo/hi halves.
    float tr = 0.0f;
    #pragma unroll
    for (int t = 0; t < 4; ++t) {
        const int k0 = 2 * t, k1 = 2 * t + 1;

        // D' rows k0,k1: ONE b128 each (fp16), issued early to hide latency
        half8 hd0 = *(const half8*)(D2T + cols[k0] * TSTRH + eoff);
        half8 hd1 = *(const half8*)(D2T + cols[k1] * TSTRH + eoff);

        // forward: y2[i] = { y_{k0}[i], y_{k1}[i] }, y = L^-1 e_k
        v2f y2[NS];
        y2[k0] = (v2f){1.0f, 0.0f};
        y2[k1] = (v2f){-getel2(A2[k1], k0), 1.0f};
        #pragma unroll
        for (int i = k1 + 1; i < NS; ++i) {
            v2f acc = (v2f){0.0f, 0.0f};
            #pragma unroll
            for (int j = k0; j < i; ++j)
                acc = pkfma(bc2(getel2(A2[i], j)), y2[j], acc);
            y2[i] = -acc;
        }

        // back: U x = y
        v2f x2[NS];
        #pragma unroll
        for (int i = NS - 1; i >= 0; --i) {
            v2f acc = (i >= k0) ? y2[i] : (v2f){0.0f, 0.0f};
            #pragma unroll
            for (int c2 = i + 1; c2 < NS; ++c2)
                acc = pkfma(-bc2(getel2(A2[i], c2)), x2[c2], acc);
            x2[i] = acc * bc2(getel2(A2[i], i));
        }

        #pragma unroll
        for (int i = 0; i < NS; ++i) {
            tr = fmaf(x2[i].x, (float)hd0[i], tr);
            tr = fmaf(x2[i].y, (float)hd1[i], tr);
        }
    }

    det_out = det;
    tr_out  = tr;
}

// Block = 256 threads = 4 spin-pure waves: w0=(b0,up) w1=(b0,dn) w2=(b1,up)
// w3=(b1,dn); lane = config index. Staging keeps the 128-threads-per-batch
// split (tid>>7 == wave>>1, so each wave solves the batch it staged).
__global__ __launch_bounds__(256)
void kp_dh_kernel(const float* __restrict__ MO,
                  const float* __restrict__ d2MO,
                  const int*   __restrict__ cfg_up,
                  const int*   __restrict__ cfg_dn,
                  float*       __restrict__ out)
{
    __shared__ float    smemA[2][TSZ];       // [batch-half][MO^T fp32, 32 x 20]
    __shared__ _Float16 smemD[2][TSZH];      // [batch-half][d2MO^T fp16, 32 x 24]
    __shared__ float    xtr [2][NCONF];      // dn -> up exchange
    __shared__ float    xdet[2][NCONF];

    const int tid  = threadIdx.x;
    const int half = tid >> 7;               // batch within block (0/1)
    const int u    = tid & 127;              // id within the batch's 128 threads
    const int b    = blockIdx.x * 2 + half;  // batch index

    float*    MOT = smemA[half];
    _Float16* D2T = smemD[half];

    const float* MOb = MO   + (size_t)b * NELEC * NMO;
    const float* d2b = d2MO + (size_t)b * NELEC * NMO;

    // Stage MO^T (fp32) and d2MO^T (fp16): column-quad per thread.
    // Global: 4 scalar dwords per array; for fixed quad-row the 32 lanes of
    // an r0-group cover 32 consecutive dwords -> 2x128B segments per instr.
    // LDS: one b128 (A) + one b64 (D) per thread, 64 distinct addresses
    // spread uniformly over banks (~12 cyc), replacing 8 conflicted
    // b32/b16 scatter writes (~73 cyc/wave).
    {
        const int c  = u & 31;               // mo column
        const int r0 = (u >> 5) << 2;        // electron quad base {0,4,8,12}
        const float* pa = MOb + r0 * NMO + c;
        const float* pd = d2b + r0 * NMO + c;
        float a0 = pa[0 * NMO], a1 = pa[1 * NMO], a2 = pa[2 * NMO], a3 = pa[3 * NMO];
        float d0 = pd[0 * NMO], d1 = pd[1 * NMO], d2 = pd[2 * NMO], d3 = pd[3 * NMO];
        *(float4*)(MOT + c * TSTR + r0) = make_float4(a0, a1, a2, a3);
        *(half4*)(D2T + c * TSTRH + r0) =
            (half4){(_Float16)d0, (_Float16)d1, (_Float16)d2, (_Float16)d3};
    }

    // Per-thread config load + in-register Batcher-8 sort with parity sign.
    const int s    = (tid >> 6) & 1;         // 0 = up wave, 1 = dn wave
    const int cidx = tid & 63;               // config index = lane
    const int* cfg = s ? cfg_dn : cfg_up;
    int4 q0 = ((const int4*)cfg)[cidx * 2 + 0];
    int4 q1 = ((const int4*)cfg)[cidx * 2 + 1];
    int cols[NS] = {q0.x, q0.y, q0.z, q0.w, q1.x, q1.y, q1.z, q1.w};
    int sgn = 0;
    #define CE(i, j) { int ai = cols[i], aj = cols[j]; int sw = ai > aj; \
                       cols[i] = sw ? aj : ai; cols[j] = sw ? ai : aj; sgn ^= sw; }
    // sort 0-3 and 4-7
    CE(0,1) CE(2,3) CE(0,2) CE(1,3) CE(1,2)
    CE(4,5) CE(6,7) CE(4,6) CE(5,7) CE(5,6)
    // Batcher odd-even merge 4+4
    CE(0,4) CE(2,6) CE(2,4)
    CE(1,5) CE(3,7) CE(3,5)
    CE(1,2) CE(3,4) CE(5,6)
    #undef CE
    const float fsign = sgn ? -1.0f : 1.0f;

    __syncthreads();

    float det, tr;
    solve8T(MOT, D2T, cols, s * NS, det, tr);
    det *= fsign;                            // undo column-sort parity

    // spin combine: dn waves publish, up waves finalize (coalesced store)
    if (s) { xtr[half][cidx] = tr; xdet[half][cidx] = det; }
    __syncthreads();
    if (!s)
        out[(size_t)b * NCONF + cidx] =
            -0.5f * (tr + xtr[half][cidx]) * det * xdet[half][cidx];
}

extern "C" void kernel_launch(void* const* d_in, const int* in_sizes, int n_in,
                              void* d_out, int out_size, void* d_ws, size_t ws_size,
                              hipStream_t stream)
{
    const float* MO     = (const float*)d_in[0];
    const float* d2MO   = (const float*)d_in[1];
    const int*   cfg_up = (const int*)d_in[2];
    const int*   cfg_dn = (const int*)d_in[3];
    float* out = (float*)d_out;

    dim3 grid(NBATCH / 2);   // 4096 blocks, 2 batches per block
    dim3 block(256);
    kp_dh_kernel<<<grid, block, 0, stream>>>(MO, d2MO, cfg_up, cfg_dn, out);
}